// Round 1
// baseline (437.882 us; speedup 1.0000x reference)
//
#include <hip/hip_runtime.h>

#define CI   128
#define TT   8192
#define CO   256
#define KW   9
#define NQ   5
#define PADL 4
#define KDIM (CI*KW)       // 1152
#define NSTEP (KDIM/32)    // 36
#define BCO  128
#define BT   128
#define XROWS (BT+8)       // 136
#define XPITCH 144         // 136 cols used (128 data), +pad -> 288B row stride, bank-balanced
#define WPITCH 40          // 32 data + 8 pad -> 80B row stride, bank-balanced

typedef __attribute__((ext_vector_type(8))) short short8;
typedef __attribute__((ext_vector_type(4))) float float4v;

static __device__ __forceinline__ short f2bf(float f) {
  union { float f; unsigned u; } c; c.f = f;
  unsigned u = c.u;
  unsigned r = (u + 0x7FFFu + ((u >> 16) & 1u)) >> 16;  // RNE
  return (short)r;
}

// ---- kernel 1: conv_weights (CO,CI,KW,NQ) fp32 -> wT[q][co][k*128+ci] bf16 ----
__global__ void selfonn_wtrans(const float* __restrict__ w, short* __restrict__ wT, int n) {
  int o = blockIdx.x * 256 + threadIdx.x;
  if (o >= n) return;
  int ci = o & (CI - 1);
  int k  = (o >> 7) % KW;
  int co = (o / KDIM) & (CO - 1);
  int q  = o / (KDIM * CO);
  wT[o] = f2bf(w[((co * CI + ci) * KW + k) * NQ + q]);
}

// ---- kernel 2: fused implicit-GEMM conv + nonlinearities + weighted sum ----
__global__ __launch_bounds__(256, 2) void selfonn_main(
    const float* __restrict__ x, const short* __restrict__ wT,
    const float* __restrict__ probs, float* __restrict__ out) {

  __shared__ __align__(16) short xs[XROWS][XPITCH];
  __shared__ __align__(16) short ws[2][BCO][WPITCH];
  __shared__ float opw[BCO][NQ];

  const int tid  = threadIdx.x;
  const int lane = tid & 63;
  const int wid  = tid >> 6;
  const int wm   = wid >> 1;   // 0..1 : which 64-co half
  const int wn   = wid & 1;    // 0..1 : which 64-t half
  const int l15  = lane & 15;
  const int lg   = lane >> 4;  // 0..3
  const int b    = blockIdx.z;
  const int co0  = blockIdx.y * BCO;
  const int t0   = blockIdx.x * BT;

  // operator softmax -> LDS
  if (tid < BCO) {
    float p[NQ];
    float mx = -1e30f;
    #pragma unroll
    for (int j = 0; j < NQ; ++j) { p[j] = probs[(co0 + tid) * NQ + j]; mx = fmaxf(mx, p[j]); }
    float s = 0.f;
    #pragma unroll
    for (int j = 0; j < NQ; ++j) { p[j] = __expf(p[j] - mx); s += p[j]; }
    float inv = 1.0f / s;
    #pragma unroll
    for (int j = 0; j < NQ; ++j) opw[tid][j] = p[j] * inv;
  }

  // stage x tile (t-transposed, bf16): xs[tl][ci] = x[b][ci][t0-4+tl]
  const float* xb = x + (size_t)b * CI * TT;
  #pragma unroll
  for (int it = 0; it < 17; ++it) {
    int cell = tid + it * 256;          // 0..4351
    int ci = cell & (CI - 1);
    int tc = cell >> 7;                 // 0..33
    int tg = t0 - PADL + tc * 4;
    float4v v = {0.f, 0.f, 0.f, 0.f};
    if (tg >= 0 && tg <= TT - 4)
      v = *(const float4v*)(xb + (size_t)ci * TT + tg);
    int tl = tc * 4;
    xs[tl + 0][ci] = f2bf(v[0]);
    xs[tl + 1][ci] = f2bf(v[1]);
    xs[tl + 2][ci] = f2bf(v[2]);
    xs[tl + 3][ci] = f2bf(v[3]);
  }

  float4v oacc[4][4];
  #pragma unroll
  for (int m = 0; m < 4; ++m)
    #pragma unroll
    for (int n = 0; n < 4; ++n)
      oacc[m][n] = (float4v){0.f, 0.f, 0.f, 0.f};

  for (int q = 0; q < NQ; ++q) {
    float4v acc[4][4];
    #pragma unroll
    for (int m = 0; m < 4; ++m)
      #pragma unroll
      for (int n = 0; n < 4; ++n)
        acc[m][n] = (float4v){0.f, 0.f, 0.f, 0.f};

    const short* wqp = wT + ((size_t)q * CO + co0) * KDIM;

    for (int chunk = 0; chunk < NSTEP / 2; ++chunk) {
      __syncthreads();  // protect ws (and xs on first iter)
      // stage 2 K-steps of weights: ws[sc][co_l][0..31] = wT row chunk
      #pragma unroll
      for (int sc = 0; sc < 2; ++sc) {
        int step = chunk * 2 + sc;
        #pragma unroll
        for (int r = 0; r < 2; ++r) {
          int idx = tid + r * 256;       // 0..511
          int co_l = idx >> 2;           // 0..127
          int part = idx & 3;
          short8 wv = *(const short8*)(wqp + (size_t)co_l * KDIM + step * 32 + part * 8);
          *(short8*)&ws[sc][co_l][part * 8] = wv;
        }
      }
      __syncthreads();

      #pragma unroll
      for (int sc = 0; sc < 2; ++sc) {
        int step = chunk * 2 + sc;
        int k   = step >> 2;             // conv tap 0..8
        int ci0 = (step & 3) * 32;       // ci block
        short8 af[4], bfv[4];
        #pragma unroll
        for (int m = 0; m < 4; ++m)
          af[m] = *(const short8*)&ws[sc][wm * 64 + m * 16 + l15][8 * lg];
        #pragma unroll
        for (int n = 0; n < 4; ++n)
          bfv[n] = *(const short8*)&xs[wn * 64 + n * 16 + l15 + k][ci0 + 8 * lg];
        #pragma unroll
        for (int m = 0; m < 4; ++m)
          #pragma unroll
          for (int n = 0; n < 4; ++n)
            acc[m][n] = __builtin_amdgcn_mfma_f32_16x16x32_bf16(af[m], bfv[n], acc[m][n], 0, 0, 0);
      }
    }

    // fused epilogue for this q
    #pragma unroll
    for (int m = 0; m < 4; ++m) {
      #pragma unroll
      for (int jj = 0; jj < 4; ++jj) {
        int co_l = wm * 64 + m * 16 + lg * 4 + jj;
        float wqv = opw[co_l][q];
        #pragma unroll
        for (int n = 0; n < 4; ++n) {
          float z = acc[m][n][jj];
          float f;
          if (q == 0)      f = z;
          else if (q == 1) f = __sinf(z);
          else if (q == 2) f = __cosf(z);
          else if (q == 3) { float e = __expf(2.f * z); f = (e - 1.f) / (e + 1.f); }
          else             { float zc = fminf(fmaxf(z, -8.f), 8.f); f = __expf(zc); }
          oacc[m][n][jj] += wqv * f;
        }
      }
    }
  }

  // store (B, CO, T) fp32
  float* ob = out + (size_t)(b * CO + co0) * TT;
  #pragma unroll
  for (int m = 0; m < 4; ++m) {
    #pragma unroll
    for (int jj = 0; jj < 4; ++jj) {
      int co_l = wm * 64 + m * 16 + lg * 4 + jj;
      int tcol = t0 + wn * 64 + l15;
      float* orow = ob + (size_t)co_l * TT + tcol;
      #pragma unroll
      for (int n = 0; n < 4; ++n)
        orow[n * 16] = oacc[m][n][jj];
    }
  }
}

extern "C" void kernel_launch(void* const* d_in, const int* in_sizes, int n_in,
                              void* d_out, int out_size, void* d_ws, size_t ws_size,
                              hipStream_t stream) {
  const float* x     = (const float*)d_in[0];
  const float* w     = (const float*)d_in[1];
  const float* probs = (const float*)d_in[2];
  float* out = (float*)d_out;
  short* wT  = (short*)d_ws;   // needs NQ*CO*KDIM*2 = 2.95 MB

  int nw = NQ * CO * KDIM;     // 1,474,560
  selfonn_wtrans<<<dim3((nw + 255) / 256), 256, 0, stream>>>(w, wT, nw);

  dim3 grid(TT / BT, CO / BCO, 16);
  selfonn_main<<<grid, 256, 0, stream>>>(x, wT, probs, out);
}

// Round 2
// 418.130 us; speedup vs baseline: 1.0472x; 1.0472x over previous
//
#include <hip/hip_runtime.h>

#define CI   128
#define TT   8192
#define CO   256
#define KW   9
#define NQ   5
#define PADL 4
#define KDIM (CI*KW)       // 1152
#define NSTEP (KDIM/32)    // 36
#define NCHUNK (NSTEP/2)   // 18 chunks of 2 K-steps
#define NF (NQ*NCHUNK)     // 90 pipelined iterations
#define BCO  128
#define BT   128
#define XROWS 136
#define XPITCH 136         // 272B row stride = 17 x 16B slots (odd) -> uniform slot spread

typedef __attribute__((ext_vector_type(8))) short short8;
typedef __attribute__((ext_vector_type(4))) float float4v;
typedef __attribute__((address_space(1))) const unsigned int ga_u32;
typedef __attribute__((address_space(3))) unsigned int la_u32;

static __device__ __forceinline__ short f2bf(float f) {
  union { float f; unsigned u; } c; c.f = f;
  unsigned u = c.u;
  unsigned r = (u + 0x7FFFu + ((u >> 16) & 1u)) >> 16;  // RNE
  return (short)r;
}

static __device__ __forceinline__ float tanh_fast(float z) {
  float e = __expf(2.f * z);
  return (e - 1.f) / (e + 1.f);
}

static __device__ __forceinline__ void gload_lds16(const void* g, void* l) {
  __builtin_amdgcn_global_load_lds((ga_u32*)g, (la_u32*)l, 16, 0, 0);
}

// ---- kernel 1: conv_weights (CO,CI,KW,NQ) fp32 -> wT[q][co][k*128+ci] bf16 ----
__global__ void selfonn_wtrans(const float* __restrict__ w, short* __restrict__ wT, int n) {
  int o = blockIdx.x * 256 + threadIdx.x;
  if (o >= n) return;
  int ci = o & (CI - 1);
  int k  = (o >> 7) % KW;
  int co = (o / KDIM) & (CO - 1);
  int q  = o / (KDIM * CO);
  wT[o] = f2bf(w[((co * CI + ci) * KW + k) * NQ + q]);
}

// ---- kernel 2: fused implicit-GEMM conv + nonlinearities + weighted sum ----
__global__ __launch_bounds__(256, 2) void selfonn_main(
    const float* __restrict__ x, const short* __restrict__ wT,
    const float* __restrict__ probs, float* __restrict__ out) {

  __shared__ __align__(16) short xs[XROWS][XPITCH];
  __shared__ __align__(16) short ws[2][2][BCO][32];  // [buf][sc][co][k] linear for gload_lds
  __shared__ float opw[BCO][NQ];

  const int tid  = threadIdx.x;
  const int lane = tid & 63;
  const int wid  = tid >> 6;
  const int wm   = wid >> 1;   // which 64-co half
  const int wn   = wid & 1;    // which 64-t half
  const int l15  = lane & 15;
  const int lg   = lane >> 4;  // 0..3
  const int b    = blockIdx.z;
  const int co0  = blockIdx.y * BCO;
  const int t0   = blockIdx.x * BT;

  // operator softmax -> LDS
  if (tid < BCO) {
    float p[NQ];
    float mx = -1e30f;
    #pragma unroll
    for (int j = 0; j < NQ; ++j) { p[j] = probs[(co0 + tid) * NQ + j]; mx = fmaxf(mx, p[j]); }
    float s = 0.f;
    #pragma unroll
    for (int j = 0; j < NQ; ++j) { p[j] = __expf(p[j] - mx); s += p[j]; }
    float inv = 1.0f / s;
    #pragma unroll
    for (int j = 0; j < NQ; ++j) opw[tid][j] = p[j] * inv;
  }

  // stage x tile once (t-transposed, bf16): xs[tl][ci] = x[b][ci][t0-4+tl]
  const float* xb = x + (size_t)b * CI * TT;
  #pragma unroll
  for (int it = 0; it < 17; ++it) {
    int cell = tid + it * 256;          // 0..4351
    int ci = cell & (CI - 1);
    int tc = cell >> 7;                 // 0..33
    int tg = t0 - PADL + tc * 4;
    float4v v = {0.f, 0.f, 0.f, 0.f};
    if (tg >= 0 && tg <= TT - 4)
      v = *(const float4v*)(xb + (size_t)ci * TT + tg);
    int tl = tc * 4;
    xs[tl + 0][ci] = f2bf(v[0]);
    xs[tl + 1][ci] = f2bf(v[1]);
    xs[tl + 2][ci] = f2bf(v[2]);
    xs[tl + 3][ci] = f2bf(v[3]);
  }

  // DMA-stage one chunk (2 K-steps = 16KB) of weights for iteration fi into ws[buf]
  auto stage = [&](int fi, int buf) {
    int q     = fi / NCHUNK;
    int chunk = fi - q * NCHUNK;
    const short* wqp = wT + ((size_t)q * CO + co0) * KDIM + chunk * 64;
    short* lb = &ws[buf][0][0][0];
    #pragma unroll
    for (int r = 0; r < 4; ++r) {
      int idx_l = r * 256 + tid;        // 0..1023, lane-contiguous 16B cells
      int sc    = idx_l >> 9;
      int rem   = idx_l & 511;
      int co_l  = rem >> 2;
      int part  = rem & 3;
      const short* src = wqp + (size_t)co_l * KDIM + sc * 32 + part * 8;
      gload_lds16(src, lb + (size_t)(r * 256 + wid * 64) * 8);  // HW adds lane*16B
    }
  };

  float4v oacc[4][4];
  float4v acc[4][4];
  #pragma unroll
  for (int m = 0; m < 4; ++m)
    #pragma unroll
    for (int n = 0; n < 4; ++n) {
      oacc[m][n] = (float4v){0.f, 0.f, 0.f, 0.f};
      acc[m][n]  = (float4v){0.f, 0.f, 0.f, 0.f};
    }

  stage(0, 0);
  __syncthreads();   // drains DMA + covers xs/opw writes

  int cur = 0;
  for (int fi = 0; fi < NF; ++fi) {
    if (fi + 1 < NF) stage(fi + 1, cur ^ 1);   // issue next chunk's DMA first

    int q     = fi / NCHUNK;
    int chunk = fi - q * NCHUNK;

    #pragma unroll
    for (int sc = 0; sc < 2; ++sc) {
      int step = chunk * 2 + sc;
      int k    = step >> 2;              // conv tap 0..8
      int ci0  = (step & 3) * 32;        // ci block
      short8 af[4], bfv[4];
      #pragma unroll
      for (int m = 0; m < 4; ++m)
        af[m] = *(const short8*)&ws[cur][sc][wm * 64 + m * 16 + l15][8 * lg];
      #pragma unroll
      for (int n = 0; n < 4; ++n)
        bfv[n] = *(const short8*)&xs[wn * 64 + n * 16 + l15 + k][ci0 + 8 * lg];
      #pragma unroll
      for (int m = 0; m < 4; ++m)
        #pragma unroll
        for (int n = 0; n < 4; ++n)
          acc[m][n] = __builtin_amdgcn_mfma_f32_16x16x32_bf16(af[m], bfv[n], acc[m][n], 0, 0, 0);
    }

    if (chunk == NCHUNK - 1) {
      // fused epilogue for this q; also resets acc
      #define DO_EPI(FEXPR)                                            \
        _Pragma("unroll") for (int m = 0; m < 4; ++m) {                \
          _Pragma("unroll") for (int jj = 0; jj < 4; ++jj) {           \
            int co_l = wm * 64 + m * 16 + lg * 4 + jj;                 \
            float wqv = opw[co_l][q];                                  \
            _Pragma("unroll") for (int n = 0; n < 4; ++n) {            \
              float z = acc[m][n][jj];                                 \
              float f = (FEXPR);                                       \
              oacc[m][n][jj] += wqv * f;                               \
              acc[m][n][jj] = 0.f;                                     \
            }                                                          \
          }                                                            \
        }
      if (q == 0)      { DO_EPI(z) }
      else if (q == 1) { DO_EPI(__sinf(z)) }
      else if (q == 2) { DO_EPI(__cosf(z)) }
      else if (q == 3) { DO_EPI(tanh_fast(z)) }
      else             { DO_EPI(__expf(fminf(fmaxf(z, -8.f), 8.f))) }
      #undef DO_EPI
    }

    __syncthreads();   // vmcnt(0)+lgkmcnt(0) drain + barrier: buf[cur^1] ready
    cur ^= 1;
  }

  // store (B, CO, T) fp32
  float* ob = out + (size_t)(b * CO + co0) * TT;
  #pragma unroll
  for (int m = 0; m < 4; ++m) {
    #pragma unroll
    for (int jj = 0; jj < 4; ++jj) {
      int co_l = wm * 64 + m * 16 + lg * 4 + jj;
      int tcol = t0 + wn * 64 + l15;
      float* orow = ob + (size_t)co_l * TT + tcol;
      #pragma unroll
      for (int n = 0; n < 4; ++n)
        orow[n * 16] = oacc[m][n][jj];
    }
  }
}

extern "C" void kernel_launch(void* const* d_in, const int* in_sizes, int n_in,
                              void* d_out, int out_size, void* d_ws, size_t ws_size,
                              hipStream_t stream) {
  const float* x     = (const float*)d_in[0];
  const float* w     = (const float*)d_in[1];
  const float* probs = (const float*)d_in[2];
  float* out = (float*)d_out;
  short* wT  = (short*)d_ws;   // NQ*CO*KDIM*2 = 2.95 MB

  int nw = NQ * CO * KDIM;
  selfonn_wtrans<<<dim3((nw + 255) / 256), 256, 0, stream>>>(w, wT, nw);

  dim3 grid(TT / BT, CO / BCO, 16);
  selfonn_main<<<grid, 256, 0, stream>>>(x, wT, probs, out);
}